// Round 1
// baseline (296.435 us; speedup 1.0000x reference)
//
#include <hip/hip_runtime.h>
#include <stdint.h>

// Multi-head Hyena conv, MFMA flash-attention form, round 11:
//   S^T[m][l] = sum_d1 v[d1,m]*x1[d1,l]       mfma 16x16x32 (K=8 valid)
//   P[l][m]   = S * k[l-m]   (sliding f32x4 gate window, zero => causal)
//   O^T[d2][l] += x2 . P^T                    mfma 16x16x32 (full K=32)
// Round-11 changes (latency-bound diagnosis: MfmaUtil 28% + VALUBusy 56%,
// occupancy 47%, HBM 14% -- nothing saturated, barriers+staging latency):
//   1. T14 async-STAGE split: next chunk's v/x2/k global loads issued into
//      registers DURING current chunk's compute; top-of-chunk is pack+ds_write
//      only. Raw s_barrier + explicit lgkmcnt(0) (no vmcnt drain!) so the
//      prefetch stays in flight across the barrier. Read-only globals =>
//      skipping the vmcnt drain is safe; LDS hazards covered by lgkmcnt.
//   2. ks[] LDS prefix buffer dropped (8KB): gate window reads k straight
//      from global (L2-resident, prefetched async like v/x2).
//   3. __launch_bounds__(256,6): 6 blocks/CU (LDS 13.6KB -> 81KB/CU),
//      VGPR cap ~84 holds 48 base + ~20 staging regs without spill.
// Gating stays v_pk_mul_f32 + v_perm trunc-pack (round-9 proven).
// Shapes fixed by setup: B=2, D=1024, L=2048, NH=8, H=128.

typedef __attribute__((ext_vector_type(8))) short bf16x8;
typedef __attribute__((ext_vector_type(4))) float f32x4;
typedef __attribute__((ext_vector_type(2))) float f32x2;

#define NHd  8
#define SC   128     // m superchunk staged in LDS
#define GW   256     // gate window: l-m spans [l0b-s0-127, l0b-s0+127]

static __device__ __forceinline__ uint32_t pkbf(float a, float b) {
    // RNE-ish pack {bf16(a) lo, bf16(b) hi}; +0x8000 rounds (ties away)
    const uint32_t ua = __float_as_uint(a) + 0x8000u;
    const uint32_t ub = __float_as_uint(b) + 0x8000u;
    return __builtin_amdgcn_perm(ub, ua, 0x07060302u);
}

static __device__ __forceinline__ uint32_t pktr(f32x2 p) {
    // truncation pack: upper 16 bits of each f32 -> {lo,hi} bf16 (1 v_perm)
    union { f32x2 f; uint32_t u[2]; } c; c.f = p;
    return __builtin_amdgcn_perm(c.u[1], c.u[0], 0x07060302u);
}

// gate two S values by two k values: v_pk_mul_f32 + v_perm (2 inst)
static __device__ __forceinline__ uint32_t gmul2(f32x2 s, f32x2 g) {
    return pktr(s * g);
}

union U8 { uint32_t u[4]; bf16x8 v; uint4 q; };

__global__ __launch_bounds__(256, 6) void hyena_mfma11_kernel(
    const float* __restrict__ v, const float* __restrict__ kf,
    const float* __restrict__ bias, const float* __restrict__ x1,
    const float* __restrict__ x2, float* __restrict__ out,
    int B, int H, int L)
{
    __shared__ __align__(16) float4 gwin[GW];           // sliding gate window
    __shared__ __align__(16) ushort vT[2][SC][NHd];     // [b][m][d1] bf16
    __shared__ __align__(16) ushort x2T[2][NHd][136];   // [b][d2][pi(m)] bf16
    __shared__ float sbuf[2][128];                      // skip gate per (b,l)

    const int tid  = threadIdx.x;
    const int h    = blockIdx.x;
    const int l0b  = ((int)gridDim.y - 1 - (int)blockIdx.y) * 128; // big-l first
    const int nk   = l0b + 128;

    const int lane = tid & 63, wv = tid >> 6;
    const int lq   = lane & 15, quad = lane >> 4;
    const int wb   = wv & 1;                // batch handled by this wave
    const int wseg = wv >> 1;               // which 64-l half of the block
    const int wl0  = l0b + wseg * 64;       // wave's 64-l range start
    const int baseb = (wb * H + h) * NHd * L;

    // ---------- fixed staging coordinates ----------
    const int sb_b   = tid >> 7, sb_row = tid & 127;
    const int sb_bs  = (sb_b * H + h) * NHd * L;
    const float* vp0 = v + sb_bs + sb_row;
    const int sb_d2  = sb_row >> 4, sb_ms = (sb_row & 15) * 8;
    const int sb_G   = sb_ms & ~31;                 // 32-group base
    const int sb_o   = sb_ms & 31;                  // 0,8,16,24
    const int sb_pa  = ((sb_o >> 2) & 3) * 8 + (sb_o >> 4) * 4;
    const float* xp0 = x2 + sb_bs + sb_d2 * L + sb_ms;
    const float* kp  = kf + h * L;
    const int gi0    = l0b - 127 + tid;             // k idx of gwin[tid] @ s0=0

    // ---------- async stage registers (one chunk in flight) ----------
    float  fv0, fv1, fv2, fv3, fv4, fv5, fv6, fv7;  // v column, 8 x d1
    float4 q0, q1;                                   // x2 8-run
    float  kg0 = 0.f, kg1 = 0.f, kg2 = 0.f, kg3 = 0.f; // gate window entry

    auto issue_stage = [&](int s0) {
        const float* vp = vp0 + s0;
        fv0 = vp[0 * L]; fv1 = vp[1 * L]; fv2 = vp[2 * L]; fv3 = vp[3 * L];
        fv4 = vp[4 * L]; fv5 = vp[5 * L]; fv6 = vp[6 * L]; fv7 = vp[7 * L];
        q0 = *(const float4*)(xp0 + s0);
        q1 = *(const float4*)(xp0 + s0 + 4);
        if (tid < GW - 1) {
            const int i = gi0 - s0;
            if (i >= 3) {
                kg0 = kp[i]; kg1 = kp[i - 1]; kg2 = kp[i - 2]; kg3 = kp[i - 3];
            } else {
                kg0 = kg1 = kg2 = kg3 = 0.f;
                if (i >= 0) kg0 = kp[i];
                if (i >= 1) kg1 = kp[i - 1];
                if (i >= 2) kg2 = kp[i - 2];
            }
        }
    };

    // ---------- prologue ----------
    issue_stage(0);   // chunk-0 loads fly under xf/sbuf build below

    // xf fragments (mfma1 B operand) for 4 l-subtiles, packed in registers
    bf16x8 xf[4] = {};
    if (quad == 0) {
#pragma unroll
        for (int j = 0; j < 4; ++j) {
            float a0[NHd];
#pragma unroll
            for (int d1 = 0; d1 < NHd; ++d1)
                a0[d1] = x1[baseb + d1 * L + wl0 + 16 * j + lq];
            U8 u0;
#pragma unroll
            for (int t = 0; t < 4; ++t) u0.u[t] = pkbf(a0[2 * t], a0[2 * t + 1]);
            xf[j] = u0.v;
        }
    }

    // skip-term gate, both b, 128 l (all 256 threads)
    {
        const int bb = tid >> 7, l = tid & 127;
        const int bs = (bb * H + h) * NHd * L;
        float s = 0.f;
#pragma unroll
        for (int d1 = 0; d1 < NHd; ++d1)
            s += bias[h * NHd + d1] * x1[bs + d1 * L + l0b + l]
                                    * v [bs + d1 * L + l0b + l];
        sbuf[bb][l] = s;
    }

    f32x4 acc[4];
#pragma unroll
    for (int j = 0; j < 4; ++j) acc[j] = (f32x4){0.f, 0.f, 0.f, 0.f};

    const int wlmax = wl0 + 63;
    // gate window coordinate (s0-independent): e = ebase - c
    const int ebase = 127 + wseg * 64 + lq - 4 * quad;

    bool gfirst = true;
    float4 g0, g1, g2, g3, g4;   // 5-deep gate file; carries across s0 too

    for (int s0 = 0; s0 < nk; s0 += SC) {
        // barrier A: previous chunk's LDS readers done. Own ds ops drained via
        // lgkmcnt only -- async global loads stay in flight (no vmcnt drain).
        asm volatile("s_waitcnt lgkmcnt(0)" ::: "memory");
        __builtin_amdgcn_s_barrier();

        // ---- write-late: pack staged regs, ds_write ----
        *(uint4*)&vT[sb_b][sb_row][0] = make_uint4(
            pkbf(fv0, fv1), pkbf(fv2, fv3), pkbf(fv4, fv5), pkbf(fv6, fv7));
        *(uint2*)&x2T[sb_b][sb_d2][sb_G + sb_pa] =
            make_uint2(pkbf(q0.x, q0.y), pkbf(q0.z, q0.w));
        *(uint2*)&x2T[sb_b][sb_d2][sb_G + sb_pa + 8] =
            make_uint2(pkbf(q1.x, q1.y), pkbf(q1.z, q1.w));
        // gwin[e] = {k[i],k[i-1],k[i-2],k[i-3]}, i = l0b-s0-127+e; entry 255
        // never read (max read index 254) -> skip.
        if (tid < GW - 1)
            gwin[tid] = make_float4(kg0, kg1, kg2, kg3);

        // ---- issue-early: next chunk's global loads fly under compute ----
        if (s0 + SC < nk) issue_stage(s0 + SC);

        // barrier B: staging visible. ds_writes drained via lgkmcnt; the
        // just-issued global loads are NOT drained.
        asm volatile("s_waitcnt lgkmcnt(0)" ::: "memory");
        __builtin_amdgcn_s_barrier();

        // wave-uniform trip count, multiple of 32 (wseg0: 64 at diagonal)
        const int cmax = min(SC, wlmax - s0 + 1);
        for (int c = 0; c < cmax; c += 32) {
            const int e = ebase - c;

            // ---- loads first (independent) ----
            bf16x8 av0 = {}, av1 = {};
            if (quad == 0) {
                av0 = *(const bf16x8*)&vT[wb][c + lq][0];
                av1 = *(const bf16x8*)&vT[wb][c + 16 + lq][0];
            }
            // gate file: subtile j: lo = g(e+16j), hi = g(e+16j-16)
            if (gfirst) {
                g4 = *(const float4*)&gwin[e + 48];
                g3 = *(const float4*)&gwin[e + 32];
                g2 = *(const float4*)&gwin[e + 16];
                gfirst = false;
            } else { g4 = g2; g3 = g1; g2 = g0; }
            g1 = *(const float4*)&gwin[e];
            g0 = *(const float4*)&gwin[e - 16];
            const bf16x8 ax = *(const bf16x8*)&x2T[wb][lq & 7][c + 8 * quad];

            const f32x4 Z = {0.f, 0.f, 0.f, 0.f};
            // ---- subtile pair 0,1 ----
            {
                const f32x4 Sa0 = __builtin_amdgcn_mfma_f32_16x16x32_bf16(av0, xf[0], Z, 0, 0, 0);
                const f32x4 Sa1 = __builtin_amdgcn_mfma_f32_16x16x32_bf16(av1, xf[0], Z, 0, 0, 0);
                const f32x4 Sb0 = __builtin_amdgcn_mfma_f32_16x16x32_bf16(av0, xf[1], Z, 0, 0, 0);
                const f32x4 Sb1 = __builtin_amdgcn_mfma_f32_16x16x32_bf16(av1, xf[1], Z, 0, 0, 0);
                U8 p;
                p.u[0] = gmul2((f32x2){Sa0[0], Sa0[1]}, (f32x2){g1.x, g1.y});
                p.u[1] = gmul2((f32x2){Sa0[2], Sa0[3]}, (f32x2){g1.z, g1.w});
                p.u[2] = gmul2((f32x2){Sa1[0], Sa1[1]}, (f32x2){g0.x, g0.y});
                p.u[3] = gmul2((f32x2){Sa1[2], Sa1[3]}, (f32x2){g0.z, g0.w});
                acc[0] = __builtin_amdgcn_mfma_f32_16x16x32_bf16(ax, p.v, acc[0], 0, 0, 0);
                p.u[0] = gmul2((f32x2){Sb0[0], Sb0[1]}, (f32x2){g2.x, g2.y});
                p.u[1] = gmul2((f32x2){Sb0[2], Sb0[3]}, (f32x2){g2.z, g2.w});
                p.u[2] = gmul2((f32x2){Sb1[0], Sb1[1]}, (f32x2){g1.x, g1.y});
                p.u[3] = gmul2((f32x2){Sb1[2], Sb1[3]}, (f32x2){g1.z, g1.w});
                acc[1] = __builtin_amdgcn_mfma_f32_16x16x32_bf16(ax, p.v, acc[1], 0, 0, 0);
            }
            // ---- subtile pair 2,3 ----
            {
                const f32x4 Sc0 = __builtin_amdgcn_mfma_f32_16x16x32_bf16(av0, xf[2], Z, 0, 0, 0);
                const f32x4 Sc1 = __builtin_amdgcn_mfma_f32_16x16x32_bf16(av1, xf[2], Z, 0, 0, 0);
                const f32x4 Sd0 = __builtin_amdgcn_mfma_f32_16x16x32_bf16(av0, xf[3], Z, 0, 0, 0);
                const f32x4 Sd1 = __builtin_amdgcn_mfma_f32_16x16x32_bf16(av1, xf[3], Z, 0, 0, 0);
                U8 p;
                p.u[0] = gmul2((f32x2){Sc0[0], Sc0[1]}, (f32x2){g3.x, g3.y});
                p.u[1] = gmul2((f32x2){Sc0[2], Sc0[3]}, (f32x2){g3.z, g3.w});
                p.u[2] = gmul2((f32x2){Sc1[0], Sc1[1]}, (f32x2){g2.x, g2.y});
                p.u[3] = gmul2((f32x2){Sc1[2], Sc1[3]}, (f32x2){g2.z, g2.w});
                acc[2] = __builtin_amdgcn_mfma_f32_16x16x32_bf16(ax, p.v, acc[2], 0, 0, 0);
                p.u[0] = gmul2((f32x2){Sd0[0], Sd0[1]}, (f32x2){g4.x, g4.y});
                p.u[1] = gmul2((f32x2){Sd0[2], Sd0[3]}, (f32x2){g4.z, g4.w});
                p.u[2] = gmul2((f32x2){Sd1[0], Sd1[1]}, (f32x2){g3.x, g3.y});
                p.u[3] = gmul2((f32x2){Sd1[2], Sd1[3]}, (f32x2){g3.z, g3.w});
                acc[3] = __builtin_amdgcn_mfma_f32_16x16x32_bf16(ax, p.v, acc[3], 0, 0, 0);
            }
        }
    }

    // ---------- epilogue: O^T layout: lane (quad,lq): d2 = 4*quad+r, l = lq ----
    if (quad < 2) {
#pragma unroll
        for (int j = 0; j < 4; ++j) {
            const int lA  = wl0 + 16 * j + lq;
            const float sb = sbuf[wb][wseg * 64 + 16 * j + lq];
#pragma unroll
            for (int r = 0; r < 4; ++r) {
                const int ro = baseb + (4 * quad + r) * L + lA;
                out[ro] = acc[j][r] + x2[ro] * sb;
            }
        }
    }
}

extern "C" void kernel_launch(void* const* d_in, const int* in_sizes, int n_in,
                              void* d_out, int out_size, void* d_ws, size_t ws_size,
                              hipStream_t stream) {
    const float* v    = (const float*)d_in[0];
    const float* k    = (const float*)d_in[1];
    const float* bias = (const float*)d_in[2];
    const float* x1   = (const float*)d_in[3];
    const float* x2   = (const float*)d_in[4];
    float* out = (float*)d_out;

    const int D = in_sizes[2];            // 1024
    const int H = D / NHd;                // 128
    const int L = in_sizes[1] / H;        // 2048
    const int B = in_sizes[0] / (D * L);  // 2

    dim3 grid(H, L / 128);
    hyena_mfma11_kernel<<<grid, 256, 0, stream>>>(v, k, bias, x1, x2, out, B, H, L);
}

// Round 2
// 256.322 us; speedup vs baseline: 1.1565x; 1.1565x over previous
//
#include <hip/hip_runtime.h>
#include <stdint.h>

// Multi-head Hyena conv, MFMA flash-attention form, round 12:
//   S^T[m][l] = sum_d1 v[d1,m]*x1[d1,l]       mfma 16x16x32 (K=8 valid)
//   P[l][m]   = S * k[l-m]   (sliding f32x4 gate window, zero => causal)
//   O^T[d2][l] += x2 . P^T                    mfma 16x16x32 (full K=32)
// Round-12: round-11's async-STAGE split kept, but __launch_bounds__
// reverted (256,6) -> (256,5). Round-11 spilled catastrophically under the
// 6-wave VGPR cap (WRITE_SIZE 33->407MB, MfmaUtil 28->10%) -- round-7
// lesson confirmed a second time: never tighten the register budget here.
// Structure under test (carried from round 11):
//   1. T14 async-STAGE split: next chunk's v/x2/k global loads issued into
//      registers DURING current chunk's compute; top-of-chunk is pack+ds_write
//      only. Raw s_barrier + explicit lgkmcnt(0) (no vmcnt drain!) so the
//      prefetch stays in flight across the barrier. Read-only globals =>
//      skipping the vmcnt drain is safe; LDS hazards covered by lgkmcnt.
//   2. ks[] LDS prefix buffer dropped (8KB): gate window reads k straight
//      from global (L2-resident, prefetched async like v/x2).
// Gating stays v_pk_mul_f32 + v_perm trunc-pack (round-9 proven).
// Shapes fixed by setup: B=2, D=1024, L=2048, NH=8, H=128.

typedef __attribute__((ext_vector_type(8))) short bf16x8;
typedef __attribute__((ext_vector_type(4))) float f32x4;
typedef __attribute__((ext_vector_type(2))) float f32x2;

#define NHd  8
#define SC   128     // m superchunk staged in LDS
#define GW   256     // gate window: l-m spans [l0b-s0-127, l0b-s0+127]

static __device__ __forceinline__ uint32_t pkbf(float a, float b) {
    // RNE-ish pack {bf16(a) lo, bf16(b) hi}; +0x8000 rounds (ties away)
    const uint32_t ua = __float_as_uint(a) + 0x8000u;
    const uint32_t ub = __float_as_uint(b) + 0x8000u;
    return __builtin_amdgcn_perm(ub, ua, 0x07060302u);
}

static __device__ __forceinline__ uint32_t pktr(f32x2 p) {
    // truncation pack: upper 16 bits of each f32 -> {lo,hi} bf16 (1 v_perm)
    union { f32x2 f; uint32_t u[2]; } c; c.f = p;
    return __builtin_amdgcn_perm(c.u[1], c.u[0], 0x07060302u);
}

// gate two S values by two k values: v_pk_mul_f32 + v_perm (2 inst)
static __device__ __forceinline__ uint32_t gmul2(f32x2 s, f32x2 g) {
    return pktr(s * g);
}

union U8 { uint32_t u[4]; bf16x8 v; uint4 q; };

__global__ __launch_bounds__(256, 5) void hyena_mfma12_kernel(
    const float* __restrict__ v, const float* __restrict__ kf,
    const float* __restrict__ bias, const float* __restrict__ x1,
    const float* __restrict__ x2, float* __restrict__ out,
    int B, int H, int L)
{
    __shared__ __align__(16) float4 gwin[GW];           // sliding gate window
    __shared__ __align__(16) ushort vT[2][SC][NHd];     // [b][m][d1] bf16
    __shared__ __align__(16) ushort x2T[2][NHd][136];   // [b][d2][pi(m)] bf16
    __shared__ float sbuf[2][128];                      // skip gate per (b,l)

    const int tid  = threadIdx.x;
    const int h    = blockIdx.x;
    const int l0b  = ((int)gridDim.y - 1 - (int)blockIdx.y) * 128; // big-l first
    const int nk   = l0b + 128;

    const int lane = tid & 63, wv = tid >> 6;
    const int lq   = lane & 15, quad = lane >> 4;
    const int wb   = wv & 1;                // batch handled by this wave
    const int wseg = wv >> 1;               // which 64-l half of the block
    const int wl0  = l0b + wseg * 64;       // wave's 64-l range start
    const int baseb = (wb * H + h) * NHd * L;

    // ---------- fixed staging coordinates ----------
    const int sb_b   = tid >> 7, sb_row = tid & 127;
    const int sb_bs  = (sb_b * H + h) * NHd * L;
    const float* vp0 = v + sb_bs + sb_row;
    const int sb_d2  = sb_row >> 4, sb_ms = (sb_row & 15) * 8;
    const int sb_G   = sb_ms & ~31;                 // 32-group base
    const int sb_o   = sb_ms & 31;                  // 0,8,16,24
    const int sb_pa  = ((sb_o >> 2) & 3) * 8 + (sb_o >> 4) * 4;
    const float* xp0 = x2 + sb_bs + sb_d2 * L + sb_ms;
    const float* kp  = kf + h * L;
    const int gi0    = l0b - 127 + tid;             // k idx of gwin[tid] @ s0=0

    // ---------- async stage registers (one chunk in flight) ----------
    float  fv0, fv1, fv2, fv3, fv4, fv5, fv6, fv7;  // v column, 8 x d1
    float4 q0, q1;                                   // x2 8-run
    float  kg0 = 0.f, kg1 = 0.f, kg2 = 0.f, kg3 = 0.f; // gate window entry

    auto issue_stage = [&](int s0) {
        const float* vp = vp0 + s0;
        fv0 = vp[0 * L]; fv1 = vp[1 * L]; fv2 = vp[2 * L]; fv3 = vp[3 * L];
        fv4 = vp[4 * L]; fv5 = vp[5 * L]; fv6 = vp[6 * L]; fv7 = vp[7 * L];
        q0 = *(const float4*)(xp0 + s0);
        q1 = *(const float4*)(xp0 + s0 + 4);
        if (tid < GW - 1) {
            const int i = gi0 - s0;
            if (i >= 3) {
                kg0 = kp[i]; kg1 = kp[i - 1]; kg2 = kp[i - 2]; kg3 = kp[i - 3];
            } else {
                kg0 = kg1 = kg2 = kg3 = 0.f;
                if (i >= 0) kg0 = kp[i];
                if (i >= 1) kg1 = kp[i - 1];
                if (i >= 2) kg2 = kp[i - 2];
            }
        }
    };

    // ---------- prologue ----------
    issue_stage(0);   // chunk-0 loads fly under xf/sbuf build below

    // xf fragments (mfma1 B operand) for 4 l-subtiles, packed in registers
    bf16x8 xf[4] = {};
    if (quad == 0) {
#pragma unroll
        for (int j = 0; j < 4; ++j) {
            float a0[NHd];
#pragma unroll
            for (int d1 = 0; d1 < NHd; ++d1)
                a0[d1] = x1[baseb + d1 * L + wl0 + 16 * j + lq];
            U8 u0;
#pragma unroll
            for (int t = 0; t < 4; ++t) u0.u[t] = pkbf(a0[2 * t], a0[2 * t + 1]);
            xf[j] = u0.v;
        }
    }

    // skip-term gate, both b, 128 l (all 256 threads)
    {
        const int bb = tid >> 7, l = tid & 127;
        const int bs = (bb * H + h) * NHd * L;
        float s = 0.f;
#pragma unroll
        for (int d1 = 0; d1 < NHd; ++d1)
            s += bias[h * NHd + d1] * x1[bs + d1 * L + l0b + l]
                                    * v [bs + d1 * L + l0b + l];
        sbuf[bb][l] = s;
    }

    f32x4 acc[4];
#pragma unroll
    for (int j = 0; j < 4; ++j) acc[j] = (f32x4){0.f, 0.f, 0.f, 0.f};

    const int wlmax = wl0 + 63;
    // gate window coordinate (s0-independent): e = ebase - c
    const int ebase = 127 + wseg * 64 + lq - 4 * quad;

    bool gfirst = true;
    float4 g0, g1, g2, g3, g4;   // 5-deep gate file; carries across s0 too

    for (int s0 = 0; s0 < nk; s0 += SC) {
        // barrier A: previous chunk's LDS readers done. Own ds ops drained via
        // lgkmcnt only -- async global loads stay in flight (no vmcnt drain).
        asm volatile("s_waitcnt lgkmcnt(0)" ::: "memory");
        __builtin_amdgcn_s_barrier();

        // ---- write-late: pack staged regs, ds_write ----
        *(uint4*)&vT[sb_b][sb_row][0] = make_uint4(
            pkbf(fv0, fv1), pkbf(fv2, fv3), pkbf(fv4, fv5), pkbf(fv6, fv7));
        *(uint2*)&x2T[sb_b][sb_d2][sb_G + sb_pa] =
            make_uint2(pkbf(q0.x, q0.y), pkbf(q0.z, q0.w));
        *(uint2*)&x2T[sb_b][sb_d2][sb_G + sb_pa + 8] =
            make_uint2(pkbf(q1.x, q1.y), pkbf(q1.z, q1.w));
        // gwin[e] = {k[i],k[i-1],k[i-2],k[i-3]}, i = l0b-s0-127+e; entry 255
        // never read (max read index 254) -> skip.
        if (tid < GW - 1)
            gwin[tid] = make_float4(kg0, kg1, kg2, kg3);

        // ---- issue-early: next chunk's global loads fly under compute ----
        if (s0 + SC < nk) issue_stage(s0 + SC);

        // barrier B: staging visible. ds_writes drained via lgkmcnt; the
        // just-issued global loads are NOT drained.
        asm volatile("s_waitcnt lgkmcnt(0)" ::: "memory");
        __builtin_amdgcn_s_barrier();

        // wave-uniform trip count, multiple of 32 (wseg0: 64 at diagonal)
        const int cmax = min(SC, wlmax - s0 + 1);
        for (int c = 0; c < cmax; c += 32) {
            const int e = ebase - c;

            // ---- loads first (independent) ----
            bf16x8 av0 = {}, av1 = {};
            if (quad == 0) {
                av0 = *(const bf16x8*)&vT[wb][c + lq][0];
                av1 = *(const bf16x8*)&vT[wb][c + 16 + lq][0];
            }
            // gate file: subtile j: lo = g(e+16j), hi = g(e+16j-16)
            if (gfirst) {
                g4 = *(const float4*)&gwin[e + 48];
                g3 = *(const float4*)&gwin[e + 32];
                g2 = *(const float4*)&gwin[e + 16];
                gfirst = false;
            } else { g4 = g2; g3 = g1; g2 = g0; }
            g1 = *(const float4*)&gwin[e];
            g0 = *(const float4*)&gwin[e - 16];
            const bf16x8 ax = *(const bf16x8*)&x2T[wb][lq & 7][c + 8 * quad];

            const f32x4 Z = {0.f, 0.f, 0.f, 0.f};
            // ---- subtile pair 0,1 ----
            {
                const f32x4 Sa0 = __builtin_amdgcn_mfma_f32_16x16x32_bf16(av0, xf[0], Z, 0, 0, 0);
                const f32x4 Sa1 = __builtin_amdgcn_mfma_f32_16x16x32_bf16(av1, xf[0], Z, 0, 0, 0);
                const f32x4 Sb0 = __builtin_amdgcn_mfma_f32_16x16x32_bf16(av0, xf[1], Z, 0, 0, 0);
                const f32x4 Sb1 = __builtin_amdgcn_mfma_f32_16x16x32_bf16(av1, xf[1], Z, 0, 0, 0);
                U8 p;
                p.u[0] = gmul2((f32x2){Sa0[0], Sa0[1]}, (f32x2){g1.x, g1.y});
                p.u[1] = gmul2((f32x2){Sa0[2], Sa0[3]}, (f32x2){g1.z, g1.w});
                p.u[2] = gmul2((f32x2){Sa1[0], Sa1[1]}, (f32x2){g0.x, g0.y});
                p.u[3] = gmul2((f32x2){Sa1[2], Sa1[3]}, (f32x2){g0.z, g0.w});
                acc[0] = __builtin_amdgcn_mfma_f32_16x16x32_bf16(ax, p.v, acc[0], 0, 0, 0);
                p.u[0] = gmul2((f32x2){Sb0[0], Sb0[1]}, (f32x2){g2.x, g2.y});
                p.u[1] = gmul2((f32x2){Sb0[2], Sb0[3]}, (f32x2){g2.z, g2.w});
                p.u[2] = gmul2((f32x2){Sb1[0], Sb1[1]}, (f32x2){g1.x, g1.y});
                p.u[3] = gmul2((f32x2){Sb1[2], Sb1[3]}, (f32x2){g1.z, g1.w});
                acc[1] = __builtin_amdgcn_mfma_f32_16x16x32_bf16(ax, p.v, acc[1], 0, 0, 0);
            }
            // ---- subtile pair 2,3 ----
            {
                const f32x4 Sc0 = __builtin_amdgcn_mfma_f32_16x16x32_bf16(av0, xf[2], Z, 0, 0, 0);
                const f32x4 Sc1 = __builtin_amdgcn_mfma_f32_16x16x32_bf16(av1, xf[2], Z, 0, 0, 0);
                const f32x4 Sd0 = __builtin_amdgcn_mfma_f32_16x16x32_bf16(av0, xf[3], Z, 0, 0, 0);
                const f32x4 Sd1 = __builtin_amdgcn_mfma_f32_16x16x32_bf16(av1, xf[3], Z, 0, 0, 0);
                U8 p;
                p.u[0] = gmul2((f32x2){Sc0[0], Sc0[1]}, (f32x2){g3.x, g3.y});
                p.u[1] = gmul2((f32x2){Sc0[2], Sc0[3]}, (f32x2){g3.z, g3.w});
                p.u[2] = gmul2((f32x2){Sc1[0], Sc1[1]}, (f32x2){g2.x, g2.y});
                p.u[3] = gmul2((f32x2){Sc1[2], Sc1[3]}, (f32x2){g2.z, g2.w});
                acc[2] = __builtin_amdgcn_mfma_f32_16x16x32_bf16(ax, p.v, acc[2], 0, 0, 0);
                p.u[0] = gmul2((f32x2){Sd0[0], Sd0[1]}, (f32x2){g4.x, g4.y});
                p.u[1] = gmul2((f32x2){Sd0[2], Sd0[3]}, (f32x2){g4.z, g4.w});
                p.u[2] = gmul2((f32x2){Sd1[0], Sd1[1]}, (f32x2){g3.x, g3.y});
                p.u[3] = gmul2((f32x2){Sd1[2], Sd1[3]}, (f32x2){g3.z, g3.w});
                acc[3] = __builtin_amdgcn_mfma_f32_16x16x32_bf16(ax, p.v, acc[3], 0, 0, 0);
            }
        }
    }

    // ---------- epilogue: O^T layout: lane (quad,lq): d2 = 4*quad+r, l = lq ----
    if (quad < 2) {
#pragma unroll
        for (int j = 0; j < 4; ++j) {
            const int lA  = wl0 + 16 * j + lq;
            const float sb = sbuf[wb][wseg * 64 + 16 * j + lq];
#pragma unroll
            for (int r = 0; r < 4; ++r) {
                const int ro = baseb + (4 * quad + r) * L + lA;
                out[ro] = acc[j][r] + x2[ro] * sb;
            }
        }
    }
}

extern "C" void kernel_launch(void* const* d_in, const int* in_sizes, int n_in,
                              void* d_out, int out_size, void* d_ws, size_t ws_size,
                              hipStream_t stream) {
    const float* v    = (const float*)d_in[0];
    const float* k    = (const float*)d_in[1];
    const float* bias = (const float*)d_in[2];
    const float* x1   = (const float*)d_in[3];
    const float* x2   = (const float*)d_in[4];
    float* out = (float*)d_out;

    const int D = in_sizes[2];            // 1024
    const int H = D / NHd;                // 128
    const int L = in_sizes[1] / H;        // 2048
    const int B = in_sizes[0] / (D * L);  // 2

    dim3 grid(H, L / 128);
    hyena_mfma12_kernel<<<grid, 256, 0, stream>>>(v, k, bias, x1, x2, out, B, H, L);
}

// Round 3
// 148.076 us; speedup vs baseline: 2.0019x; 1.7310x over previous
//
#include <hip/hip_runtime.h>
#include <stdint.h>

// Multi-head Hyena conv, MFMA flash-attention form, round 13:
//   S^T[m][l] = sum_d1 v[d1,m]*x1[d1,l]       mfma 16x16x32 (K=8 valid)
//   P[l][m]   = S * k[l-m]   (sliding f32x4 gate window, zero => causal)
//   O^T[d2][l] += x2 . P^T                    mfma 16x16x32 (full K=32)
// Round-13: single change vs round 12: __launch_bounds__(256,5) -> (256,4).
// The async-STAGE split keeps ~20 staged values live across the whole
// compute phase; at the 5-wave cap (~102 VGPR) the allocator spilled ~3-4
// regs/inner-iter (round-12: WRITE 273MB vs 33MB clean). (256,4) caps at
// 128 VGPR (>= ~115 live estimate) and its occupancy ceiling (16 waves/CU
// = 50%) matches round-10's MEASURED 47.75% -- loosening costs ~nothing.
// Structure under test (carried from rounds 11/12, still never run clean):
//   1. T14 async-STAGE split: next chunk's v/x2/k global loads issued into
//      registers DURING current chunk's compute; top-of-chunk is pack+ds_write
//      only. Raw s_barrier + explicit lgkmcnt(0) (no vmcnt drain!) so the
//      prefetch stays in flight across the barrier. Read-only globals =>
//      skipping the vmcnt drain is safe; LDS hazards covered by lgkmcnt.
//   2. ks[] LDS prefix buffer dropped (8KB): gate window reads k straight
//      from global (L2-resident, prefetched async like v/x2).
// Gating stays v_pk_mul_f32 + v_perm trunc-pack (round-9 proven).
// Shapes fixed by setup: B=2, D=1024, L=2048, NH=8, H=128.

typedef __attribute__((ext_vector_type(8))) short bf16x8;
typedef __attribute__((ext_vector_type(4))) float f32x4;
typedef __attribute__((ext_vector_type(2))) float f32x2;

#define NHd  8
#define SC   128     // m superchunk staged in LDS
#define GW   256     // gate window: l-m spans [l0b-s0-127, l0b-s0+127]

static __device__ __forceinline__ uint32_t pkbf(float a, float b) {
    // RNE-ish pack {bf16(a) lo, bf16(b) hi}; +0x8000 rounds (ties away)
    const uint32_t ua = __float_as_uint(a) + 0x8000u;
    const uint32_t ub = __float_as_uint(b) + 0x8000u;
    return __builtin_amdgcn_perm(ub, ua, 0x07060302u);
}

static __device__ __forceinline__ uint32_t pktr(f32x2 p) {
    // truncation pack: upper 16 bits of each f32 -> {lo,hi} bf16 (1 v_perm)
    union { f32x2 f; uint32_t u[2]; } c; c.f = p;
    return __builtin_amdgcn_perm(c.u[1], c.u[0], 0x07060302u);
}

// gate two S values by two k values: v_pk_mul_f32 + v_perm (2 inst)
static __device__ __forceinline__ uint32_t gmul2(f32x2 s, f32x2 g) {
    return pktr(s * g);
}

union U8 { uint32_t u[4]; bf16x8 v; uint4 q; };

__global__ __launch_bounds__(256, 4) void hyena_mfma13_kernel(
    const float* __restrict__ v, const float* __restrict__ kf,
    const float* __restrict__ bias, const float* __restrict__ x1,
    const float* __restrict__ x2, float* __restrict__ out,
    int B, int H, int L)
{
    __shared__ __align__(16) float4 gwin[GW];           // sliding gate window
    __shared__ __align__(16) ushort vT[2][SC][NHd];     // [b][m][d1] bf16
    __shared__ __align__(16) ushort x2T[2][NHd][136];   // [b][d2][pi(m)] bf16
    __shared__ float sbuf[2][128];                      // skip gate per (b,l)

    const int tid  = threadIdx.x;
    const int h    = blockIdx.x;
    const int l0b  = ((int)gridDim.y - 1 - (int)blockIdx.y) * 128; // big-l first
    const int nk   = l0b + 128;

    const int lane = tid & 63, wv = tid >> 6;
    const int lq   = lane & 15, quad = lane >> 4;
    const int wb   = wv & 1;                // batch handled by this wave
    const int wseg = wv >> 1;               // which 64-l half of the block
    const int wl0  = l0b + wseg * 64;       // wave's 64-l range start
    const int baseb = (wb * H + h) * NHd * L;

    // ---------- fixed staging coordinates ----------
    const int sb_b   = tid >> 7, sb_row = tid & 127;
    const int sb_bs  = (sb_b * H + h) * NHd * L;
    const float* vp0 = v + sb_bs + sb_row;
    const int sb_d2  = sb_row >> 4, sb_ms = (sb_row & 15) * 8;
    const int sb_G   = sb_ms & ~31;                 // 32-group base
    const int sb_o   = sb_ms & 31;                  // 0,8,16,24
    const int sb_pa  = ((sb_o >> 2) & 3) * 8 + (sb_o >> 4) * 4;
    const float* xp0 = x2 + sb_bs + sb_d2 * L + sb_ms;
    const float* kp  = kf + h * L;
    const int gi0    = l0b - 127 + tid;             // k idx of gwin[tid] @ s0=0

    // ---------- async stage registers (one chunk in flight) ----------
    float  fv0, fv1, fv2, fv3, fv4, fv5, fv6, fv7;  // v column, 8 x d1
    float4 q0, q1;                                   // x2 8-run
    float  kg0 = 0.f, kg1 = 0.f, kg2 = 0.f, kg3 = 0.f; // gate window entry

    auto issue_stage = [&](int s0) {
        const float* vp = vp0 + s0;
        fv0 = vp[0 * L]; fv1 = vp[1 * L]; fv2 = vp[2 * L]; fv3 = vp[3 * L];
        fv4 = vp[4 * L]; fv5 = vp[5 * L]; fv6 = vp[6 * L]; fv7 = vp[7 * L];
        q0 = *(const float4*)(xp0 + s0);
        q1 = *(const float4*)(xp0 + s0 + 4);
        if (tid < GW - 1) {
            const int i = gi0 - s0;
            if (i >= 3) {
                kg0 = kp[i]; kg1 = kp[i - 1]; kg2 = kp[i - 2]; kg3 = kp[i - 3];
            } else {
                kg0 = kg1 = kg2 = kg3 = 0.f;
                if (i >= 0) kg0 = kp[i];
                if (i >= 1) kg1 = kp[i - 1];
                if (i >= 2) kg2 = kp[i - 2];
            }
        }
    };

    // ---------- prologue ----------
    issue_stage(0);   // chunk-0 loads fly under xf/sbuf build below

    // xf fragments (mfma1 B operand) for 4 l-subtiles, packed in registers
    bf16x8 xf[4] = {};
    if (quad == 0) {
#pragma unroll
        for (int j = 0; j < 4; ++j) {
            float a0[NHd];
#pragma unroll
            for (int d1 = 0; d1 < NHd; ++d1)
                a0[d1] = x1[baseb + d1 * L + wl0 + 16 * j + lq];
            U8 u0;
#pragma unroll
            for (int t = 0; t < 4; ++t) u0.u[t] = pkbf(a0[2 * t], a0[2 * t + 1]);
            xf[j] = u0.v;
        }
    }

    // skip-term gate, both b, 128 l (all 256 threads)
    {
        const int bb = tid >> 7, l = tid & 127;
        const int bs = (bb * H + h) * NHd * L;
        float s = 0.f;
#pragma unroll
        for (int d1 = 0; d1 < NHd; ++d1)
            s += bias[h * NHd + d1] * x1[bs + d1 * L + l0b + l]
                                    * v [bs + d1 * L + l0b + l];
        sbuf[bb][l] = s;
    }

    f32x4 acc[4];
#pragma unroll
    for (int j = 0; j < 4; ++j) acc[j] = (f32x4){0.f, 0.f, 0.f, 0.f};

    const int wlmax = wl0 + 63;
    // gate window coordinate (s0-independent): e = ebase - c
    const int ebase = 127 + wseg * 64 + lq - 4 * quad;

    bool gfirst = true;
    float4 g0, g1, g2, g3, g4;   // 5-deep gate file; carries across s0 too

    for (int s0 = 0; s0 < nk; s0 += SC) {
        // barrier A: previous chunk's LDS readers done. Own ds ops drained via
        // lgkmcnt only -- async global loads stay in flight (no vmcnt drain).
        asm volatile("s_waitcnt lgkmcnt(0)" ::: "memory");
        __builtin_amdgcn_s_barrier();

        // ---- write-late: pack staged regs, ds_write ----
        *(uint4*)&vT[sb_b][sb_row][0] = make_uint4(
            pkbf(fv0, fv1), pkbf(fv2, fv3), pkbf(fv4, fv5), pkbf(fv6, fv7));
        *(uint2*)&x2T[sb_b][sb_d2][sb_G + sb_pa] =
            make_uint2(pkbf(q0.x, q0.y), pkbf(q0.z, q0.w));
        *(uint2*)&x2T[sb_b][sb_d2][sb_G + sb_pa + 8] =
            make_uint2(pkbf(q1.x, q1.y), pkbf(q1.z, q1.w));
        // gwin[e] = {k[i],k[i-1],k[i-2],k[i-3]}, i = l0b-s0-127+e; entry 255
        // never read (max read index 254) -> skip.
        if (tid < GW - 1)
            gwin[tid] = make_float4(kg0, kg1, kg2, kg3);

        // ---- issue-early: next chunk's global loads fly under compute ----
        if (s0 + SC < nk) issue_stage(s0 + SC);

        // barrier B: staging visible. ds_writes drained via lgkmcnt; the
        // just-issued global loads are NOT drained.
        asm volatile("s_waitcnt lgkmcnt(0)" ::: "memory");
        __builtin_amdgcn_s_barrier();

        // wave-uniform trip count, multiple of 32 (wseg0: 64 at diagonal)
        const int cmax = min(SC, wlmax - s0 + 1);
        for (int c = 0; c < cmax; c += 32) {
            const int e = ebase - c;

            // ---- loads first (independent) ----
            bf16x8 av0 = {}, av1 = {};
            if (quad == 0) {
                av0 = *(const bf16x8*)&vT[wb][c + lq][0];
                av1 = *(const bf16x8*)&vT[wb][c + 16 + lq][0];
            }
            // gate file: subtile j: lo = g(e+16j), hi = g(e+16j-16)
            if (gfirst) {
                g4 = *(const float4*)&gwin[e + 48];
                g3 = *(const float4*)&gwin[e + 32];
                g2 = *(const float4*)&gwin[e + 16];
                gfirst = false;
            } else { g4 = g2; g3 = g1; g2 = g0; }
            g1 = *(const float4*)&gwin[e];
            g0 = *(const float4*)&gwin[e - 16];
            const bf16x8 ax = *(const bf16x8*)&x2T[wb][lq & 7][c + 8 * quad];

            const f32x4 Z = {0.f, 0.f, 0.f, 0.f};
            // ---- subtile pair 0,1 ----
            {
                const f32x4 Sa0 = __builtin_amdgcn_mfma_f32_16x16x32_bf16(av0, xf[0], Z, 0, 0, 0);
                const f32x4 Sa1 = __builtin_amdgcn_mfma_f32_16x16x32_bf16(av1, xf[0], Z, 0, 0, 0);
                const f32x4 Sb0 = __builtin_amdgcn_mfma_f32_16x16x32_bf16(av0, xf[1], Z, 0, 0, 0);
                const f32x4 Sb1 = __builtin_amdgcn_mfma_f32_16x16x32_bf16(av1, xf[1], Z, 0, 0, 0);
                U8 p;
                p.u[0] = gmul2((f32x2){Sa0[0], Sa0[1]}, (f32x2){g1.x, g1.y});
                p.u[1] = gmul2((f32x2){Sa0[2], Sa0[3]}, (f32x2){g1.z, g1.w});
                p.u[2] = gmul2((f32x2){Sa1[0], Sa1[1]}, (f32x2){g0.x, g0.y});
                p.u[3] = gmul2((f32x2){Sa1[2], Sa1[3]}, (f32x2){g0.z, g0.w});
                acc[0] = __builtin_amdgcn_mfma_f32_16x16x32_bf16(ax, p.v, acc[0], 0, 0, 0);
                p.u[0] = gmul2((f32x2){Sb0[0], Sb0[1]}, (f32x2){g2.x, g2.y});
                p.u[1] = gmul2((f32x2){Sb0[2], Sb0[3]}, (f32x2){g2.z, g2.w});
                p.u[2] = gmul2((f32x2){Sb1[0], Sb1[1]}, (f32x2){g1.x, g1.y});
                p.u[3] = gmul2((f32x2){Sb1[2], Sb1[3]}, (f32x2){g1.z, g1.w});
                acc[1] = __builtin_amdgcn_mfma_f32_16x16x32_bf16(ax, p.v, acc[1], 0, 0, 0);
            }
            // ---- subtile pair 2,3 ----
            {
                const f32x4 Sc0 = __builtin_amdgcn_mfma_f32_16x16x32_bf16(av0, xf[2], Z, 0, 0, 0);
                const f32x4 Sc1 = __builtin_amdgcn_mfma_f32_16x16x32_bf16(av1, xf[2], Z, 0, 0, 0);
                const f32x4 Sd0 = __builtin_amdgcn_mfma_f32_16x16x32_bf16(av0, xf[3], Z, 0, 0, 0);
                const f32x4 Sd1 = __builtin_amdgcn_mfma_f32_16x16x32_bf16(av1, xf[3], Z, 0, 0, 0);
                U8 p;
                p.u[0] = gmul2((f32x2){Sc0[0], Sc0[1]}, (f32x2){g3.x, g3.y});
                p.u[1] = gmul2((f32x2){Sc0[2], Sc0[3]}, (f32x2){g3.z, g3.w});
                p.u[2] = gmul2((f32x2){Sc1[0], Sc1[1]}, (f32x2){g2.x, g2.y});
                p.u[3] = gmul2((f32x2){Sc1[2], Sc1[3]}, (f32x2){g2.z, g2.w});
                acc[2] = __builtin_amdgcn_mfma_f32_16x16x32_bf16(ax, p.v, acc[2], 0, 0, 0);
                p.u[0] = gmul2((f32x2){Sd0[0], Sd0[1]}, (f32x2){g4.x, g4.y});
                p.u[1] = gmul2((f32x2){Sd0[2], Sd0[3]}, (f32x2){g4.z, g4.w});
                p.u[2] = gmul2((f32x2){Sd1[0], Sd1[1]}, (f32x2){g3.x, g3.y});
                p.u[3] = gmul2((f32x2){Sd1[2], Sd1[3]}, (f32x2){g3.z, g3.w});
                acc[3] = __builtin_amdgcn_mfma_f32_16x16x32_bf16(ax, p.v, acc[3], 0, 0, 0);
            }
        }
    }

    // ---------- epilogue: O^T layout: lane (quad,lq): d2 = 4*quad+r, l = lq ----
    if (quad < 2) {
#pragma unroll
        for (int j = 0; j < 4; ++j) {
            const int lA  = wl0 + 16 * j + lq;
            const float sb = sbuf[wb][wseg * 64 + 16 * j + lq];
#pragma unroll
            for (int r = 0; r < 4; ++r) {
                const int ro = baseb + (4 * quad + r) * L + lA;
                out[ro] = acc[j][r] + x2[ro] * sb;
            }
        }
    }
}

extern "C" void kernel_launch(void* const* d_in, const int* in_sizes, int n_in,
                              void* d_out, int out_size, void* d_ws, size_t ws_size,
                              hipStream_t stream) {
    const float* v    = (const float*)d_in[0];
    const float* k    = (const float*)d_in[1];
    const float* bias = (const float*)d_in[2];
    const float* x1   = (const float*)d_in[3];
    const float* x2   = (const float*)d_in[4];
    float* out = (float*)d_out;

    const int D = in_sizes[2];            // 1024
    const int H = D / NHd;                // 128
    const int L = in_sizes[1] / H;        // 2048
    const int B = in_sizes[0] / (D * L);  // 2

    dim3 grid(H, L / 128);
    hyena_mfma13_kernel<<<grid, 256, 0, stream>>>(v, k, bias, x1, x2, out, B, H, L);
}